// Round 4
// baseline (682.980 us; speedup 1.0000x reference)
//
#include <hip/hip_runtime.h>

// LIF membrane update, single fused kernel (split-K, last-block finalize):
//   v_new[b,n] = ALPHA*v[b,n] + sum_i x[b,i,n]*w[i,n] - V_TH*z[b,n]
//   z_new[b,n] = (v_new[b,n] - V_TH > 0) ? 1 : 0
// Shapes: x (128,1024,512) f32, w (1024,512) f32, v,z (128,512) f32.
// Memory-bound: x = 256 MiB read once; floor ~39-41 us at 6.5-6.9 TB/s.
//
// R3: grid = 128 b x 2 slabs x 8 igroups = 2048 blocks (8/CU, 32 waves/CU,
// 100% occupancy; launch_bounds(256,8) caps VGPR at 64). Each block: 1 batch,
// 64 f4-cols, 128 i's (c = t>>6 splits 4-way). LDS tree-reduce -> partial to
// ws. Last block per (b,slab) (atomic counter, memset to 0 each call) sums
// the 8 igroup partials in FIXED order (bit-deterministic) and applies the
// LIF update. x loads non-temporal (stream-once; keep 2MB w L2-resident).

typedef float f32x4 __attribute__((ext_vector_type(4)));

constexpr int B    = 128;
constexpr int N_IN = 1024;
constexpr int NN   = 512;
constexpr int NN4  = NN / 4;     // 128 float4 columns
constexpr int IG   = 8;          // igroups (split-K factor)
constexpr int IPG  = N_IN / IG;  // 128 i per group
constexpr int IPT  = IPG / 4;    // 32 i per thread
constexpr float ALPHA = 1.0f - 0.05f / 10.0f;  // 0.995
constexpr float V_TH  = 2.0f;

__global__ __launch_bounds__(256, 8) void lif_fused(
    const f32x4* __restrict__ x4,
    const f32x4* __restrict__ w4,
    const f32x4* __restrict__ v4,
    const f32x4* __restrict__ z4,
    f32x4* __restrict__ vout4,
    f32x4* __restrict__ zout4,
    f32x4* __restrict__ part,      // [IG][B][2][64]
    unsigned* __restrict__ cnt)    // [B*2], zeroed via memsetAsync per call
{
    const int t    = threadIdx.x;
    const int ig   = blockIdx.x & 7;
    const int slab = (blockIdx.x >> 3) & 1;
    const int b    = blockIdx.x >> 4;
    const int g    = t & 63;          // f4 column within slab
    const int c    = t >> 6;          // i-subchunk 0..3
    const int col  = slab * 64 + g;   // f4 column 0..127
    const int i0   = ig * IPG + c * IPT;

    const f32x4* __restrict__ xp = x4 + ((size_t)b * N_IN + i0) * NN4 + col;
    const f32x4* __restrict__ wp = w4 + (size_t)i0 * NN4 + col;

    f32x4 a = {0.f, 0.f, 0.f, 0.f};
    #pragma unroll 4
    for (int ii = 0; ii < IPT; ++ii) {
        f32x4 wv = wp[(size_t)ii * NN4];                               // L2-hit
        f32x4 xv = __builtin_nontemporal_load(&xp[(size_t)ii * NN4]);  // HBM stream
        a += xv * wv;
    }

    __shared__ f32x4 red[256];
    __shared__ bool lastblk;
    red[t] = a;
    __syncthreads();
    if (t < 128) red[t] += red[t + 128];
    __syncthreads();
    if (t < 64) {
        f32x4 s = red[t] + red[t + 64];
        part[(((size_t)ig * B + b) * 2 + slab) * 64 + t] = s;
    }
    // Release: each thread's fence makes its stores device-visible before
    // the sync; t0's atomic then publishes them (threadFenceReduction pattern).
    __threadfence();
    __syncthreads();
    if (t == 0) {
        unsigned old = atomicAdd(&cnt[b * 2 + slab], 1u);
        lastblk = (old == IG - 1);
    }
    __syncthreads();
    if (!lastblk) return;

    __threadfence();   // acquire: invalidate local caches before reading
                       // partials written on other XCDs
    if (t < 64) {
        f32x4 s = {0.f, 0.f, 0.f, 0.f};
        #pragma unroll
        for (int k = 0; k < IG; ++k)                     // FIXED order: deterministic
            s += part[(((size_t)k * B + b) * 2 + slab) * 64 + t];
        const int idx = b * NN4 + slab * 64 + t;
        f32x4 vv = v4[idx];
        f32x4 zz = z4[idx];
        f32x4 vn = ALPHA * vv + s - V_TH * zz;
        vout4[idx] = vn;
        f32x4 zn;
        zn.x = (vn.x - V_TH > 0.f) ? 1.f : 0.f;
        zn.y = (vn.y - V_TH > 0.f) ? 1.f : 0.f;
        zn.z = (vn.z - V_TH > 0.f) ? 1.f : 0.f;
        zn.w = (vn.w - V_TH > 0.f) ? 1.f : 0.f;
        zout4[idx] = zn;
    }
}

extern "C" void kernel_launch(void* const* d_in, const int* in_sizes, int n_in,
                              void* d_out, int out_size, void* d_ws, size_t ws_size,
                              hipStream_t stream) {
    const f32x4* x = (const f32x4*)d_in[0];
    const f32x4* w = (const f32x4*)d_in[1];
    const f32x4* v = (const f32x4*)d_in[2];
    const f32x4* z = (const f32x4*)d_in[3];
    f32x4* vout = (f32x4*)d_out;                 // v_new: B*NN floats
    f32x4* zout = vout + (size_t)B * NN4;        // z_new follows flat

    unsigned* cnt = (unsigned*)d_ws;                       // 256 counters, 1 KB
    f32x4* part = (f32x4*)((char*)d_ws + 4096);            // 2 MB partials

    hipMemsetAsync(cnt, 0, B * 2 * sizeof(unsigned), stream);
    lif_fused<<<dim3(B * 2 * IG), dim3(256), 0, stream>>>(
        x, w, v, z, vout, zout, part, cnt);
}

// Round 5
// 54.187 us; speedup vs baseline: 12.6042x; 12.6042x over previous
//
#include <hip/hip_runtime.h>

// LIF membrane update, single fused kernel (no split-K, no fences):
//   v_new[b,n] = ALPHA*v[b,n] + sum_i x[b,i,n]*w[i,n] - V_TH*z[b,n]
//   z_new[b,n] = (v_new[b,n] - V_TH > 0) ? 1 : 0
// Shapes: x (128,1024,512) f32, w (1024,512) f32, v,z (128,512) f32.
// Memory-bound: x = 268 MB read once; floor ~40 us at ~6.5 TB/s.
//
// R4: each block owns the FULL i-range for (2 batches x 16 f4-cols), so the
// output is finished in-block: no partials, no second kernel, no device
// fences (R3's agent-scope __threadfence caused L2 wbinv storms -> 683us).
// Block = 256 thr: g = t&15 (f4 col), c = t>>4 (16 i-chunks x 64 i).
// 2 batches/block amortizes w loads (1 w per 2 x). Grid = 64 bpairs x 8
// slabs = 512 blocks = 2/CU (8 waves/CU; fill kernels prove ~10% occupancy
// saturates HBM). x loads non-temporal; w stays L2-resident (2 MB).

typedef float f32x4 __attribute__((ext_vector_type(4)));

constexpr int B    = 128;
constexpr int N_IN = 1024;
constexpr int NN   = 512;
constexpr int NN4  = NN / 4;      // 128 float4 columns
constexpr float ALPHA = 1.0f - 0.05f / 10.0f;  // 0.995
constexpr float V_TH  = 2.0f;

__global__ __launch_bounds__(256) void lif_fused(
    const f32x4* __restrict__ x4,
    const f32x4* __restrict__ w4,
    const f32x4* __restrict__ v4,
    const f32x4* __restrict__ z4,
    f32x4* __restrict__ vout4,
    f32x4* __restrict__ zout4)
{
    const int t    = threadIdx.x;
    const int g    = t & 15;          // f4 column within slab
    const int c    = t >> 4;          // i-chunk 0..15, 64 i each
    const int slab = blockIdx.x & 7;  // 8 slabs of 16 f4-cols
    const int bp   = blockIdx.x >> 3; // batch pair 0..63

    const int b0  = bp * 2;
    const int col = slab * 16 + g;    // f4 column 0..127
    const int i0  = c * 64;

    const f32x4* __restrict__ xp0 = x4 + ((size_t)b0 * N_IN + i0) * NN4 + col;
    const f32x4* __restrict__ xp1 = xp0 + (size_t)N_IN * NN4;
    const f32x4* __restrict__ wp  = w4 + (size_t)i0 * NN4 + col;

    f32x4 a0 = {0.f, 0.f, 0.f, 0.f};
    f32x4 a1 = {0.f, 0.f, 0.f, 0.f};
    #pragma unroll 8
    for (int ii = 0; ii < 64; ++ii) {
        f32x4 wv  = wp[(size_t)ii * NN4];                                // L2-hit
        f32x4 xv0 = __builtin_nontemporal_load(&xp0[(size_t)ii * NN4]);  // HBM stream
        f32x4 xv1 = __builtin_nontemporal_load(&xp1[(size_t)ii * NN4]);
        a0 += xv0 * wv;
        a1 += xv1 * wv;
    }

    __shared__ f32x4 red0[256];
    __shared__ f32x4 red1[256];
    red0[t] = a0;
    red1[t] = a1;
    __syncthreads();

    // Reduce over c (t = c*16 + g): partner stride halves 128..16.
    if (t < 128) { red0[t] += red0[t + 128]; red1[t] += red1[t + 128]; }
    __syncthreads();
    if (t < 64)  { red0[t] += red0[t + 64];  red1[t] += red1[t + 64];  }
    __syncthreads();
    if (t < 32)  { red0[t] += red0[t + 32];  red1[t] += red1[t + 32];  }
    __syncthreads();

    if (t < 16) {
        f32x4 s0 = red0[t] + red0[t + 16];
        f32x4 s1 = red1[t] + red1[t + 16];
        const int cidx = slab * 16 + t;
        const int idx0 = b0 * NN4 + cidx;
        const int idx1 = idx0 + NN4;

        f32x4 vv0 = v4[idx0], zz0 = z4[idx0];
        f32x4 vv1 = v4[idx1], zz1 = z4[idx1];
        f32x4 vn0 = ALPHA * vv0 + s0 - V_TH * zz0;
        f32x4 vn1 = ALPHA * vv1 + s1 - V_TH * zz1;
        vout4[idx0] = vn0;
        vout4[idx1] = vn1;
        f32x4 zn0, zn1;
        zn0.x = (vn0.x - V_TH > 0.f) ? 1.f : 0.f;
        zn0.y = (vn0.y - V_TH > 0.f) ? 1.f : 0.f;
        zn0.z = (vn0.z - V_TH > 0.f) ? 1.f : 0.f;
        zn0.w = (vn0.w - V_TH > 0.f) ? 1.f : 0.f;
        zn1.x = (vn1.x - V_TH > 0.f) ? 1.f : 0.f;
        zn1.y = (vn1.y - V_TH > 0.f) ? 1.f : 0.f;
        zn1.z = (vn1.z - V_TH > 0.f) ? 1.f : 0.f;
        zn1.w = (vn1.w - V_TH > 0.f) ? 1.f : 0.f;
        zout4[idx0] = zn0;
        zout4[idx1] = zn1;
    }
}

extern "C" void kernel_launch(void* const* d_in, const int* in_sizes, int n_in,
                              void* d_out, int out_size, void* d_ws, size_t ws_size,
                              hipStream_t stream) {
    const f32x4* x = (const f32x4*)d_in[0];
    const f32x4* w = (const f32x4*)d_in[1];
    const f32x4* v = (const f32x4*)d_in[2];
    const f32x4* z = (const f32x4*)d_in[3];
    f32x4* vout = (f32x4*)d_out;                 // v_new: B*NN floats
    f32x4* zout = vout + (size_t)B * NN4;        // z_new follows flat

    lif_fused<<<dim3(64 * 8), dim3(256), 0, stream>>>(x, w, v, z, vout, zout);
}